// Round 7
// baseline (26020.377 us; speedup 1.0000x reference)
//
#include <hip/hip_runtime.h>
#include <hip/hip_bf16.h>

#define E_ 768
#define E2_ 1536
#define E3_ 2304
#define U_ 256
#define NORM_ 27.712812921102035f

typedef unsigned int u32;
typedef unsigned long long u64;

// ---------------- static device workspace (~8.3 MB) ----------------
__device__ __align__(16) float g_Q[U_ * E_];       // D @ Wq + bq
__device__ __align__(16) float g_WQg[U_ * E2_];    // (Wk @ q_t)/norm, row t
__device__ __align__(16) float g_WKVT[E_ * E2_];   // (Wk@Wv)^T : [e][k]
__device__ __align__(16) float g_buf[U_ * E2_];    // attention memory (atomic access)
__device__ __align__(16) float g_vb[E_];           // bk@Wv + bv
__device__ __align__(16) float g_scores[U_];
__device__ __align__(16) float g_att[E_];
__device__ __align__(16) float g_so[E2_];
__device__ __align__(16) float g_gh[E2_];
__device__ __align__(16) float g_hstate[8 * E2_];
__device__ __align__(16) int   g_flags[U_];

__device__ __forceinline__ float bflo(u32 v){ return __uint_as_float(v << 16); }
__device__ __forceinline__ float bfhi(u32 v){ return __uint_as_float(v & 0xffff0000u); }

// pack two fp32 into one u32 holding two bf16 (RNE): low 16 = first, high 16 = second
__device__ __forceinline__ u32 packbf(float lo, float hi){
  u32 a = __float_as_uint(lo), b = __float_as_uint(hi);
  a = (a + 0x7FFFu + ((a >> 16) & 1u)) >> 16;
  b = (b + 0x7FFFu + ((b >> 16) & 1u)) & 0xFFFF0000u;
  return (a & 0xFFFFu) | b;
}

// ---- agent-scope atomic access for values written by other blocks this kernel ----
__device__ __forceinline__ float aload_f(const float* p){
  u32 v = __hip_atomic_load((const u32*)p, __ATOMIC_RELAXED, __HIP_MEMORY_SCOPE_AGENT);
  return __uint_as_float(v);
}
__device__ __forceinline__ void astore_f(float* p, float v){
  __hip_atomic_store((u32*)p, __float_as_uint(v), __ATOMIC_RELAXED, __HIP_MEMORY_SCOPE_AGENT);
}
__device__ __forceinline__ float2 aload_f2(const float* p){
  u64 v = __hip_atomic_load((const u64*)p, __ATOMIC_RELAXED, __HIP_MEMORY_SCOPE_AGENT);
  float2 r; r.x = __uint_as_float((u32)v); r.y = __uint_as_float((u32)(v >> 32)); return r;
}

__device__ __forceinline__ float wsum(float v){
#pragma unroll
  for (int o = 32; o > 0; o >>= 1) v += __shfl_xor(v, o, 64);
  return v;
}
__device__ __forceinline__ float wmax(float v){
#pragma unroll
  for (int o = 32; o > 0; o >>= 1) v = fmaxf(v, __shfl_xor(v, o, 64));
  return v;
}

// ---------------- init: flags/hstate/gh (blocks 0..63), vb (blocks 64..75) ----------------
__global__ __launch_bounds__(256) void init_kernel(const float* h0g, const float* h0s,
                                                   const float* bk, const float* Wv,
                                                   const float* bv)
{
  __shared__ float acc4[4][64];
  int tid = threadIdx.x;
  if (blockIdx.x < 64) {
    int i = blockIdx.x * 256 + tid;
    int n = 64 * 256;
    for (int j = i; j < 256; j += n) g_flags[j] = 0;
    for (int j = i; j < 8 * E2_; j += n) g_hstate[j] = h0s[j % E2_];
    for (int j = i; j < E2_; j += n) g_gh[j] = h0g[j];
  } else {
    int b = blockIdx.x - 64;          // 0..11
    int o = b * 64 + (tid & 63);
    int w = tid >> 6;
    float s = 0.f;
    for (int i = w * 192; i < w * 192 + 192; ++i)
      s = fmaf(bk[i], Wv[(size_t)i * E_ + o], s);
    acc4[w][tid & 63] = s;
    __syncthreads();
    if (w == 0)
      g_vb[o] = acc4[0][tid & 63] + acc4[1][tid & 63] + acc4[2][tid & 63] + acc4[3][tid & 63] + bv[o];
  }
}

// ---------------- fp32 tiled GEMM: C = scale*(A@B) + bias ----------------
// ASRC: 0 = Aext, 1 = g_Q. BNK=1 -> B[n*ldb+k]; BNK=0 -> B[k*ldb+n].
// DST: 0=g_Q 1=g_WQg 2=g_WKVT.  TC=1 -> store C[n*ldc+m].  BIAS: bias!=null
template<int ASRC, int BNK, int DST, int TC>
__global__ __launch_bounds__(256) void gemm32(const float* __restrict__ Aext, int lda,
                                              const float* __restrict__ B, int ldb,
                                              const float* __restrict__ bias, float scale,
                                              int ldc, int M, int N, int K)
{
  const float* A = (ASRC == 1) ? g_Q : Aext;
  float* C = (DST == 0) ? g_Q : (DST == 1) ? g_WQg : g_WKVT;
  __shared__ float As[64][17];
  __shared__ float Bs[16][65];
  int tid = threadIdx.x;
  int tx = tid & 15, ty = tid >> 4;
  int m0 = blockIdx.y * 64, n0 = blockIdx.x * 64;
  float acc[4][4] = {{0.f}};
  for (int k0 = 0; k0 < K; k0 += 16) {
#pragma unroll
    for (int i = 0; i < 4; ++i) {
      int li = tid + 256 * i;
      int m = li >> 4, kk = li & 15;
      As[m][kk] = A[(size_t)(m0 + m) * lda + k0 + kk];
    }
#pragma unroll
    for (int i = 0; i < 4; ++i) {
      int li = tid + 256 * i;
      if (BNK) {
        int n = li >> 4, kk = li & 15;
        Bs[kk][n] = B[(size_t)(n0 + n) * ldb + k0 + kk];
      } else {
        int kk = li >> 6, n = li & 63;
        Bs[kk][n] = B[(size_t)(k0 + kk) * ldb + n0 + n];
      }
    }
    __syncthreads();
#pragma unroll
    for (int kk = 0; kk < 16; ++kk) {
      float av[4], bv4[4];
#pragma unroll
      for (int i = 0; i < 4; ++i) av[i] = As[ty * 4 + i][kk];
#pragma unroll
      for (int j = 0; j < 4; ++j) bv4[j] = Bs[kk][tx * 4 + j];
#pragma unroll
      for (int i = 0; i < 4; ++i)
#pragma unroll
        for (int j = 0; j < 4; ++j) acc[i][j] = fmaf(av[i], bv4[j], acc[i][j]);
    }
    __syncthreads();
  }
#pragma unroll
  for (int i = 0; i < 4; ++i)
#pragma unroll
    for (int j = 0; j < 4; ++j) {
      int m = m0 + ty * 4 + i, n = n0 + tx * 4 + j;
      float c = acc[i][j] * scale;
      if (bias) c += bias[n];
      if (TC) C[(size_t)n * ldc + m] = c;
      else    C[(size_t)m * ldc + n] = c;
    }
}

// ---------------- persistent sequential kernel ----------------
struct SeqArgs {
  const float *dialogue, *sWih_f, *sWih_b, *sWhh_f, *sWhh_b,
      *sbih_f, *sbih_b, *sbhh_f, *sbhh_b,
      *gWih_f, *gWih_b, *gWhh_f, *gWhh_b, *gbih_f, *gbih_b, *gbhh_f, *gbhh_b,
      *att0;
  const int* speakers;
  float* out;   // fp32: [U*2E buf][U*2E so]
};

__device__ __forceinline__ void gbar(int target)
{
  __syncthreads();
  if (threadIdx.x == 0) {
    __builtin_amdgcn_fence(__ATOMIC_RELEASE, "agent");
    __hip_atomic_store(&g_flags[blockIdx.x], target, __ATOMIC_RELAXED, __HIP_MEMORY_SCOPE_AGENT);
  }
  int v;
  do {
    v = __hip_atomic_load(&g_flags[threadIdx.x], __ATOMIC_RELAXED, __HIP_MEMORY_SCOPE_AGENT);
  } while (v < target);
  __builtin_amdgcn_fence(__ATOMIC_ACQUIRE, "agent");
  __syncthreads();
}

__global__ __launch_bounds__(256, 1) void seq_kernel(SeqArgs a)
{
  const int tid = threadIdx.x, wg = blockIdx.x;
  const int wave = tid >> 6, lane = tid & 63;
  const int h0 = wg * 3;

  __shared__ float ghs_s[18], ghg_s[18], sxu[18], gxu[18], gxs[18];
  __shared__ float red4[4], att_s[3], pnum[4][4], pmax[4];
  __shared__ float V_lds[U_][3];

  // ---- per-block weight slices: fp32 -> packed bf16 registers ----
  u32 wSA[5][6], wSU[5][6], wSHH[5][6], wGHH[5][6], wGSO[5][12], wGU[5][6];
  float bSH[5], bGH[5], bSI[5], bGI[5];
#pragma unroll
  for (int q = 0; q < 5; ++q) {
    int sr = wave + 4 * q;
    if (sr < 18) {
      int dir = sr / 9, lr = sr - dir * 9, g = lr / 3, d = lr - g * 3;
      int gr = g * E_ + h0 + d;
      const float* pa  = (dir ? a.sWih_b : a.sWih_f) + (size_t)gr * E2_;
      const float* ph  = (dir ? a.sWhh_b : a.sWhh_f) + (size_t)gr * E_;
      const float* pgs = (dir ? a.gWih_b : a.gWih_f) + (size_t)gr * E3_;
      const float* pgh = (dir ? a.gWhh_b : a.gWhh_f) + (size_t)gr * E_;
#pragma unroll
      for (int pp = 0; pp < 6; ++pp) {
        int j2 = 2 * (lane + 64 * pp);
        wSA[q][pp]  = packbf(pa[j2], pa[j2 + 1]);
        wSU[q][pp]  = packbf(pa[768 + j2], pa[768 + j2 + 1]);
        wSHH[q][pp] = packbf(ph[j2], ph[j2 + 1]);
        wGHH[q][pp] = packbf(pgh[j2], pgh[j2 + 1]);
        wGU[q][pp]  = packbf(pgs[1536 + j2], pgs[1536 + j2 + 1]);
      }
#pragma unroll
      for (int pp = 0; pp < 12; ++pp) {
        int j2 = 2 * (lane + 64 * pp);
        wGSO[q][pp] = packbf(pgs[j2], pgs[j2 + 1]);
      }
      bSH[q] = (dir ? a.sbhh_b : a.sbhh_f)[gr];
      bSI[q] = (dir ? a.sbih_b : a.sbih_f)[gr];
      bGH[q] = (dir ? a.gbhh_b : a.gbhh_f)[gr];
      bGI[q] = (dir ? a.gbih_b : a.gbih_f)[gr];
    }
  }
  // ---- wKV: 3 columns of Wk@Wv for this block (fp32) ----
  float wKV[24];
  if (wave < 3) {
    const float* kv = g_WKVT + (size_t)(h0 + wave) * E2_;
#pragma unroll
    for (int pp = 0; pp < 12; ++pp) {
      int j2 = 2 * (lane + 64 * pp);
      wKV[2 * pp] = kv[j2]; wKV[2 * pp + 1] = kv[j2 + 1];
    }
  }
  const float vb0 = g_vb[h0], vb1 = g_vb[h0 + 1], vb2 = g_vb[h0 + 2];

  int bt = 0;
  for (int t = 0; t < U_; ++t) {
    const int sp = a.speakers[t] & 7;
    const float2* uv = (const float2*)(a.dialogue + (size_t)t * E_);   // 384 float2

    // ---------- P0: scores, recurrent-h + u-part matvecs, V[t-1] slice ----------
    if (wg < t) {
      const float* br = g_buf + (size_t)wg * E2_;
      const float* wq = g_WQg + (size_t)t * E2_;
      float s = 0.f;
#pragma unroll
      for (int pp = 0; pp < 3; ++pp) {
        int j = tid + 256 * pp;
        float2 x = aload_f2(br + 2 * j);
        float2 w = *(const float2*)(wq + 2 * j);
        s = fmaf(x.x, w.x, s);
        s = fmaf(x.y, w.y, s);
      }
      s = wsum(s);
      if (lane == 0) red4[wave] = s;
      __syncthreads();
      if (tid == 0) astore_f(&g_scores[wg], red4[0] + red4[1] + red4[2] + red4[3]);
    } else if (wg == t) {
      if (tid == 0) astore_f(&g_scores[wg], 0.f);  // buf row t zero; const shift dropped (softmax-inv)
    }
#pragma unroll
    for (int q = 0; q < 5; ++q) {
      int sr = wave + 4 * q;
      if (sr < 18) {
        int dir = sr / 9;
        const float* hv = g_hstate + (size_t)(sp * 2 + dir) * E_;
        const float* gv = g_gh + (size_t)dir * E_;
        float s1 = 0.f, s2 = 0.f, s3 = 0.f, s4 = 0.f;
#pragma unroll
        for (int pp = 0; pp < 6; ++pp) {
          int j = lane + 64 * pp;
          u32 v1 = wSHH[q][pp], v2 = wGHH[q][pp], v3 = wSU[q][pp], v4 = wGU[q][pp];
          float2 xh = aload_f2(hv + 2 * j);
          float2 xg = aload_f2(gv + 2 * j);
          float2 xu = uv[j];
          s1 = fmaf(bflo(v1), xh.x, s1); s1 = fmaf(bfhi(v1), xh.y, s1);
          s2 = fmaf(bflo(v2), xg.x, s2); s2 = fmaf(bfhi(v2), xg.y, s2);
          s3 = fmaf(bflo(v3), xu.x, s3); s3 = fmaf(bfhi(v3), xu.y, s3);
          s4 = fmaf(bflo(v4), xu.x, s4); s4 = fmaf(bfhi(v4), xu.y, s4);
        }
        s1 = wsum(s1); s2 = wsum(s2); s3 = wsum(s3); s4 = wsum(s4);
        if (lane == 0) {
          ghs_s[sr] = s1 + bSH[q]; ghg_s[sr] = s2 + bGH[q];
          sxu[sr] = s3 + bSI[q];   gxu[sr] = s4 + bGI[q];
        }
      }
    }
    if (t > 0 && wave < 3) {
      const float* br = g_buf + (size_t)(t - 1) * E2_;
      float s = 0.f;
#pragma unroll
      for (int pp = 0; pp < 12; ++pp) {
        int j = lane + 64 * pp;
        float2 x = aload_f2(br + 2 * j);
        s = fmaf(wKV[2 * pp], x.x, s);
        s = fmaf(wKV[2 * pp + 1], x.y, s);
      }
      s = wsum(s);
      if (lane == 0) V_lds[t - 1][wave] = s + (wave == 0 ? vb0 : (wave == 1 ? vb1 : vb2));
    }
    gbar(++bt);

    // ---------- P1: max-subtracted softmax + att (3 dims per block) ----------
    if (t == 0) {
      if (tid < 3) { float v = a.att0[h0 + tid]; att_s[tid] = v; astore_f(&g_att[h0 + tid], v); }
    } else {
      float sc = (tid <= t) ? aload_f(&g_scores[tid]) : -3.0e38f;
      float m = wmax(sc);
      if (lane == 0) pmax[wave] = m;
      __syncthreads();
      float mall = fmaxf(fmaxf(pmax[0], pmax[1]), fmaxf(pmax[2], pmax[3]));
      float e = 0.f, n0 = 0.f, n1 = 0.f, n2 = 0.f;
      if (tid <= t) {
        e = expf(sc - mall);
        if (tid < t) { n0 = e * V_lds[tid][0]; n1 = e * V_lds[tid][1]; n2 = e * V_lds[tid][2]; }
        else         { n0 = e * vb0; n1 = e * vb1; n2 = e * vb2; }
      }
      e = wsum(e); n0 = wsum(n0); n1 = wsum(n1); n2 = wsum(n2);
      if (lane == 0) { pnum[wave][0] = e; pnum[wave][1] = n0; pnum[wave][2] = n1; pnum[wave][3] = n2; }
      __syncthreads();
      if (tid < 3) {
        float den = pnum[0][0] + pnum[1][0] + pnum[2][0] + pnum[3][0];
        float nn = pnum[0][tid + 1] + pnum[1][tid + 1] + pnum[2][tid + 1] + pnum[3][tid + 1];
        float v = nn / den;
        att_s[tid] = v; astore_f(&g_att[h0 + tid], v);
      }
    }
    gbar(++bt);

    // ---------- P2: speaker GRU ----------
#pragma unroll
    for (int q = 0; q < 5; ++q) {
      int sr = wave + 4 * q;
      if (sr < 18) {
        float s = 0.f;
#pragma unroll
        for (int pp = 0; pp < 6; ++pp) {
          int j = lane + 64 * pp;
          u32 v = wSA[q][pp];
          float2 x = aload_f2(g_att + 2 * j);
          s = fmaf(bflo(v), x.x, s); s = fmaf(bfhi(v), x.y, s);
        }
        s = wsum(s);
        if (lane == 0) gxs[sr] = s;
      }
    }
    __syncthreads();
    if (tid < 6) {
      int dir = tid / 3, d = tid - dir * 3, h = h0 + d;
      float xr = gxs[dir * 9 + d]     + sxu[dir * 9 + d];
      float xz = gxs[dir * 9 + 3 + d] + sxu[dir * 9 + 3 + d];
      float xn = gxs[dir * 9 + 6 + d] + sxu[dir * 9 + 6 + d];
      float hr = ghs_s[dir * 9 + d], hz = ghs_s[dir * 9 + 3 + d], hn = ghs_s[dir * 9 + 6 + d];
      float hp = aload_f(&g_hstate[(size_t)(sp * 2 + dir) * E_ + h]);
      float r = 1.f / (1.f + expf(-(xr + hr)));
      float z = 1.f / (1.f + expf(-(xz + hz)));
      float n = tanhf(xn + r * hn);
      float hnew = (1.f - z) * n + z * hp;
      astore_f(&g_hstate[(size_t)(sp * 2 + dir) * E_ + h], hnew);
      float resid = dir ? a.dialogue[(size_t)t * E_ + h] : att_s[d];
      float so = hnew + resid;
      astore_f(&g_so[dir * E_ + h], so);
      a.out[(size_t)U_ * E2_ + (size_t)t * E2_ + dir * E_ + h] = so;
    }
    gbar(++bt);

    // ---------- P3: global GRU ----------
#pragma unroll
    for (int q = 0; q < 5; ++q) {
      int sr = wave + 4 * q;
      if (sr < 18) {
        float s = 0.f;
#pragma unroll
        for (int pp = 0; pp < 12; ++pp) {
          int j = lane + 64 * pp;
          u32 v = wGSO[q][pp];
          float2 x = aload_f2(g_so + 2 * j);
          s = fmaf(bflo(v), x.x, s); s = fmaf(bfhi(v), x.y, s);
        }
        s = wsum(s);
        if (lane == 0) gxs[sr] = s;
      }
    }
    __syncthreads();
    if (tid < 6) {
      int dir = tid / 3, d = tid - dir * 3, h = h0 + d;
      float xr = gxs[dir * 9 + d]     + gxu[dir * 9 + d];
      float xz = gxs[dir * 9 + 3 + d] + gxu[dir * 9 + 3 + d];
      float xn = gxs[dir * 9 + 6 + d] + gxu[dir * 9 + 6 + d];
      float hr = ghg_s[dir * 9 + d], hz = ghg_s[dir * 9 + 3 + d], hn = ghg_s[dir * 9 + 6 + d];
      float hp = aload_f(&g_gh[dir * E_ + h]);
      float r = 1.f / (1.f + expf(-(xr + hr)));
      float z = 1.f / (1.f + expf(-(xz + hz)));
      float n = tanhf(xn + r * hn);
      float hnew = (1.f - z) * n + z * hp;
      astore_f(&g_gh[dir * E_ + h], hnew);
      astore_f(&g_buf[(size_t)t * E2_ + dir * E_ + h], hnew);
      a.out[(size_t)t * E2_ + dir * E_ + h] = hnew;
    }
    gbar(++bt);
  }
}

// ---------------- host ----------------
extern "C" void kernel_launch(void* const* d_in, const int* in_sizes, int n_in,
                              void* d_out, int out_size, void* d_ws, size_t ws_size,
                              hipStream_t stream)
{
  (void)in_sizes; (void)n_in; (void)out_size; (void)d_ws; (void)ws_size;
  const float* dialogue = (const float*)d_in[0];
  const int* speakers = (const int*)d_in[1];
  const float* Wq = (const float*)d_in[2];
  const float* bq = (const float*)d_in[3];
  const float* Wk = (const float*)d_in[4];
  const float* bk = (const float*)d_in[5];
  const float* Wv = (const float*)d_in[6];
  const float* bv = (const float*)d_in[7];
  const float* sWih_f = (const float*)d_in[8];
  const float* sWhh_f = (const float*)d_in[9];
  const float* sbih_f = (const float*)d_in[10];
  const float* sbhh_f = (const float*)d_in[11];
  const float* sWih_b = (const float*)d_in[12];
  const float* sWhh_b = (const float*)d_in[13];
  const float* sbih_b = (const float*)d_in[14];
  const float* sbhh_b = (const float*)d_in[15];
  const float* gWih_f = (const float*)d_in[16];
  const float* gWhh_f = (const float*)d_in[17];
  const float* gbih_f = (const float*)d_in[18];
  const float* gbhh_f = (const float*)d_in[19];
  const float* gWih_b = (const float*)d_in[20];
  const float* gWhh_b = (const float*)d_in[21];
  const float* gbih_b = (const float*)d_in[22];
  const float* gbhh_b = (const float*)d_in[23];
  const float* h0_global = (const float*)d_in[24];
  const float* h0_speaker = (const float*)d_in[25];
  const float* att0 = (const float*)d_in[26];

  init_kernel<<<dim3(76), dim3(256), 0, stream>>>(h0_global, h0_speaker, bk, Wv, bv);

  // g_Q = D @ Wq + bq
  gemm32<0, 0, 0, 0><<<dim3(12, 4), dim3(256), 0, stream>>>(
      dialogue, 768, Wq, 768, bq, 1.f, 768, 256, 768, 768);
  // g_WQg = g_Q @ Wk^T / norm
  gemm32<1, 1, 1, 0><<<dim3(24, 4), dim3(256), 0, stream>>>(
      nullptr, 768, Wk, 768, nullptr, 1.f / NORM_, 1536, 256, 1536, 768);
  // g_WKVT[e][k] = (Wk @ Wv)[k][e]
  gemm32<0, 0, 2, 1><<<dim3(12, 24), dim3(256), 0, stream>>>(
      Wk, 768, Wv, 768, nullptr, 1.f, 1536, 1536, 768, 768);

  SeqArgs args;
  args.dialogue = dialogue;
  args.sWih_f = sWih_f; args.sWih_b = sWih_b; args.sWhh_f = sWhh_f; args.sWhh_b = sWhh_b;
  args.sbih_f = sbih_f; args.sbih_b = sbih_b; args.sbhh_f = sbhh_f; args.sbhh_b = sbhh_b;
  args.gWih_f = gWih_f; args.gWih_b = gWih_b; args.gWhh_f = gWhh_f; args.gWhh_b = gWhh_b;
  args.gbih_f = gbih_f; args.gbih_b = gbih_b; args.gbhh_f = gbhh_f; args.gbhh_b = gbhh_b;
  args.att0 = att0; args.speakers = speakers;
  args.out = (float*)d_out;

  seq_kernel<<<dim3(256), dim3(256), 0, stream>>>(args);
}

// Round 8
// 15841.925 us; speedup vs baseline: 1.6425x; 1.6425x over previous
//
#include <hip/hip_runtime.h>
#include <hip/hip_bf16.h>

#define E_ 768
#define E2_ 1536
#define E3_ 2304
#define U_ 256
#define NORM_ 27.712812921102035f

typedef unsigned int u32;
typedef unsigned long long u64;

// ---------------- static device workspace (~8.3 MB) ----------------
__device__ __align__(16) float g_Q[U_ * E_];       // D @ Wq + bq
__device__ __align__(16) float g_WQg[U_ * E2_];    // (Wk @ q_t)/norm, row t
__device__ __align__(16) float g_WKVT[E_ * E2_];   // (Wk@Wv)^T : [e][k]
__device__ __align__(16) float g_buf[U_ * E2_];    // attention memory
__device__ __align__(16) float g_vb[E_];           // bk@Wv + bv
__device__ __align__(16) float g_scores[U_];
__device__ __align__(16) float g_att[E_];
__device__ __align__(16) float g_so[E2_];
__device__ __align__(16) float g_gh[E2_];
__device__ __align__(16) float g_hstate[8 * E2_];
__device__ int g_count;   // barrier arrival ticket counter
__device__ int g_epoch;   // barrier release epoch

__device__ __forceinline__ float bflo(u32 v){ return __uint_as_float(v << 16); }
__device__ __forceinline__ float bfhi(u32 v){ return __uint_as_float(v & 0xffff0000u); }

// pack two fp32 into one u32 holding two bf16 (RNE)
__device__ __forceinline__ u32 packbf(float lo, float hi){
  u32 a = __float_as_uint(lo), b = __float_as_uint(hi);
  a = (a + 0x7FFFu + ((a >> 16) & 1u)) >> 16;
  b = (b + 0x7FFFu + ((b >> 16) & 1u)) & 0xFFFF0000u;
  return (a & 0xFFFFu) | b;
}

__device__ __forceinline__ float wsum(float v){
#pragma unroll
  for (int o = 32; o > 0; o >>= 1) v += __shfl_xor(v, o, 64);
  return v;
}
__device__ __forceinline__ float wmax(float v){
#pragma unroll
  for (int o = 32; o > 0; o >>= 1) v = fmaxf(v, __shfl_xor(v, o, 64));
  return v;
}

// ---------------- init: barrier words, hstate/gh (blocks 0..63), vb (64..75) ----------------
__global__ __launch_bounds__(256) void init_kernel(const float* h0g, const float* h0s,
                                                   const float* bk, const float* Wv,
                                                   const float* bv)
{
  __shared__ float acc4[4][64];
  int tid = threadIdx.x;
  if (blockIdx.x < 64) {
    int i = blockIdx.x * 256 + tid;
    int n = 64 * 256;
    if (i == 0) { g_count = 0; g_epoch = 0; }
    for (int j = i; j < 8 * E2_; j += n) g_hstate[j] = h0s[j % E2_];
    for (int j = i; j < E2_; j += n) g_gh[j] = h0g[j];
  } else {
    int b = blockIdx.x - 64;          // 0..11
    int o = b * 64 + (tid & 63);
    int w = tid >> 6;
    float s = 0.f;
    for (int i2 = w * 192; i2 < w * 192 + 192; ++i2)
      s = fmaf(bk[i2], Wv[(size_t)i2 * E_ + o], s);
    acc4[w][tid & 63] = s;
    __syncthreads();
    if (w == 0)
      g_vb[o] = acc4[0][tid & 63] + acc4[1][tid & 63] + acc4[2][tid & 63] + acc4[3][tid & 63] + bv[o];
  }
}

// ---------------- fp32 tiled GEMM: C = scale*(A@B) + bias ----------------
template<int ASRC, int BNK, int DST, int TC>
__global__ __launch_bounds__(256) void gemm32(const float* __restrict__ Aext, int lda,
                                              const float* __restrict__ B, int ldb,
                                              const float* __restrict__ bias, float scale,
                                              int ldc, int M, int N, int K)
{
  const float* A = (ASRC == 1) ? g_Q : Aext;
  float* C = (DST == 0) ? g_Q : (DST == 1) ? g_WQg : g_WKVT;
  __shared__ float As[64][17];
  __shared__ float Bs[16][65];
  int tid = threadIdx.x;
  int tx = tid & 15, ty = tid >> 4;
  int m0 = blockIdx.y * 64, n0 = blockIdx.x * 64;
  float acc[4][4] = {{0.f}};
  for (int k0 = 0; k0 < K; k0 += 16) {
#pragma unroll
    for (int i = 0; i < 4; ++i) {
      int li = tid + 256 * i;
      int m = li >> 4, kk = li & 15;
      As[m][kk] = A[(size_t)(m0 + m) * lda + k0 + kk];
    }
#pragma unroll
    for (int i = 0; i < 4; ++i) {
      int li = tid + 256 * i;
      if (BNK) {
        int n = li >> 4, kk = li & 15;
        Bs[kk][n] = B[(size_t)(n0 + n) * ldb + k0 + kk];
      } else {
        int kk = li >> 6, n = li & 63;
        Bs[kk][n] = B[(size_t)(k0 + kk) * ldb + n0 + n];
      }
    }
    __syncthreads();
#pragma unroll
    for (int kk = 0; kk < 16; ++kk) {
      float av[4], bv4[4];
#pragma unroll
      for (int i = 0; i < 4; ++i) av[i] = As[ty * 4 + i][kk];
#pragma unroll
      for (int j = 0; j < 4; ++j) bv4[j] = Bs[kk][tx * 4 + j];
#pragma unroll
      for (int i = 0; i < 4; ++i)
#pragma unroll
        for (int j = 0; j < 4; ++j) acc[i][j] = fmaf(av[i], bv4[j], acc[i][j]);
    }
    __syncthreads();
  }
#pragma unroll
  for (int i = 0; i < 4; ++i)
#pragma unroll
    for (int j = 0; j < 4; ++j) {
      int m = m0 + ty * 4 + i, n = n0 + tx * 4 + j;
      float c = acc[i][j] * scale;
      if (bias) c += bias[n];
      if (TC) C[(size_t)n * ldc + m] = c;
      else    C[(size_t)m * ldc + n] = c;
    }
}

// ---------------- persistent sequential kernel ----------------
struct SeqArgs {
  const float *dialogue, *sWih_f, *sWih_b, *sWhh_f, *sWhh_b,
      *sbih_f, *sbih_b, *sbhh_f, *sbhh_b,
      *gWih_f, *gWih_b, *gWhh_f, *gWhh_b, *gbih_f, *gbih_b, *gbhh_f, *gbhh_b,
      *att0;
  const int* speakers;
  float* out;   // fp32: [U*2E buf][U*2E so]
};

// Centralized ticket barrier: one arrival counter, one epoch word.
// Only thread 0 of each block arrives and polls (s_sleep backoff); fences
// provide release/acquire (writeback + invalidate) at agent scope.
__device__ __forceinline__ void gbar(int target)
{
  __syncthreads();
  if (threadIdx.x == 0) {
    __builtin_amdgcn_fence(__ATOMIC_RELEASE, "agent");
    int t = __hip_atomic_fetch_add(&g_count, 1, __ATOMIC_RELAXED, __HIP_MEMORY_SCOPE_AGENT);
    if (t == 256 * target - 1) {
      __hip_atomic_store(&g_epoch, target, __ATOMIC_RELAXED, __HIP_MEMORY_SCOPE_AGENT);
    } else {
      while (__hip_atomic_load(&g_epoch, __ATOMIC_RELAXED, __HIP_MEMORY_SCOPE_AGENT) < target)
        __builtin_amdgcn_s_sleep(1);
    }
    __builtin_amdgcn_fence(__ATOMIC_ACQUIRE, "agent");
  }
  __syncthreads();
}

__global__ __launch_bounds__(256, 1) void seq_kernel(SeqArgs a)
{
  const int tid = threadIdx.x, wg = blockIdx.x;
  const int wave = tid >> 6, lane = tid & 63;
  const int h0 = wg * 3;

  __shared__ float ghs_s[18], ghg_s[18], sxu[18], gxu[18], gxs[18];
  __shared__ float red4[4], att_s[3], pnum[4][4], pmax[4];
  __shared__ float V_lds[U_][3];

  // ---- per-block weight slices: fp32 -> packed bf16 registers ----
  u32 wSA[5][6], wSU[5][6], wSHH[5][6], wGHH[5][6], wGSO[5][12], wGU[5][6];
  float bSH[5], bGH[5], bSI[5], bGI[5];
#pragma unroll
  for (int q = 0; q < 5; ++q) {
    int sr = wave + 4 * q;
    if (sr < 18) {
      int dir = sr / 9, lr = sr - dir * 9, g = lr / 3, d = lr - g * 3;
      int gr = g * E_ + h0 + d;
      const float* pa  = (dir ? a.sWih_b : a.sWih_f) + (size_t)gr * E2_;
      const float* ph  = (dir ? a.sWhh_b : a.sWhh_f) + (size_t)gr * E_;
      const float* pgs = (dir ? a.gWih_b : a.gWih_f) + (size_t)gr * E3_;
      const float* pgh = (dir ? a.gWhh_b : a.gWhh_f) + (size_t)gr * E_;
#pragma unroll
      for (int pp = 0; pp < 6; ++pp) {
        int j2 = 2 * (lane + 64 * pp);
        wSA[q][pp]  = packbf(pa[j2], pa[j2 + 1]);
        wSU[q][pp]  = packbf(pa[768 + j2], pa[768 + j2 + 1]);
        wSHH[q][pp] = packbf(ph[j2], ph[j2 + 1]);
        wGHH[q][pp] = packbf(pgh[j2], pgh[j2 + 1]);
        wGU[q][pp]  = packbf(pgs[1536 + j2], pgs[1536 + j2 + 1]);
      }
#pragma unroll
      for (int pp = 0; pp < 12; ++pp) {
        int j2 = 2 * (lane + 64 * pp);
        wGSO[q][pp] = packbf(pgs[j2], pgs[j2 + 1]);
      }
      bSH[q] = (dir ? a.sbhh_b : a.sbhh_f)[gr];
      bSI[q] = (dir ? a.sbih_b : a.sbih_f)[gr];
      bGH[q] = (dir ? a.gbhh_b : a.gbhh_f)[gr];
      bGI[q] = (dir ? a.gbih_b : a.gbih_f)[gr];
    }
  }
  // ---- wKV: 3 columns of Wk@Wv for this block (fp32) ----
  float wKV[24];
  if (wave < 3) {
    const float* kv = g_WKVT + (size_t)(h0 + wave) * E2_;
#pragma unroll
    for (int pp = 0; pp < 12; ++pp) {
      int j2 = 2 * (lane + 64 * pp);
      wKV[2 * pp] = kv[j2]; wKV[2 * pp + 1] = kv[j2 + 1];
    }
  }
  const float vb0 = g_vb[h0], vb1 = g_vb[h0 + 1], vb2 = g_vb[h0 + 2];

  int bt = 0;
  for (int t = 0; t < U_; ++t) {
    const int sp = a.speakers[t] & 7;
    const float2* uv = (const float2*)(a.dialogue + (size_t)t * E_);   // 384 float2

    // ---------- P0: scores, recurrent-h + u-part matvecs, V[t-1] slice ----------
    if (wg < t) {
      const float2* br = (const float2*)(g_buf + (size_t)wg * E2_);
      const float2* wq = (const float2*)(g_WQg + (size_t)t * E2_);
      float s = 0.f;
#pragma unroll
      for (int pp = 0; pp < 3; ++pp) {
        int j = tid + 256 * pp;
        float2 x = br[j];
        float2 w = wq[j];
        s = fmaf(x.x, w.x, s);
        s = fmaf(x.y, w.y, s);
      }
      s = wsum(s);
      if (lane == 0) red4[wave] = s;
      __syncthreads();
      if (tid == 0) g_scores[wg] = red4[0] + red4[1] + red4[2] + red4[3];
    } else if (wg == t) {
      if (tid == 0) g_scores[wg] = 0.f;  // buf row t zero; const shift dropped (softmax-inv)
    }
#pragma unroll
    for (int q = 0; q < 5; ++q) {
      int sr = wave + 4 * q;
      if (sr < 18) {
        int dir = sr / 9;
        const float2* hv = (const float2*)(g_hstate + (size_t)(sp * 2 + dir) * E_);
        const float2* gv = (const float2*)(g_gh + (size_t)dir * E_);
        float s1 = 0.f, s2 = 0.f, s3 = 0.f, s4 = 0.f;
#pragma unroll
        for (int pp = 0; pp < 6; ++pp) {
          int j = lane + 64 * pp;
          u32 v1 = wSHH[q][pp], v2 = wGHH[q][pp], v3 = wSU[q][pp], v4 = wGU[q][pp];
          float2 xh = hv[j];
          float2 xg = gv[j];
          float2 xu = uv[j];
          s1 = fmaf(bflo(v1), xh.x, s1); s1 = fmaf(bfhi(v1), xh.y, s1);
          s2 = fmaf(bflo(v2), xg.x, s2); s2 = fmaf(bfhi(v2), xg.y, s2);
          s3 = fmaf(bflo(v3), xu.x, s3); s3 = fmaf(bfhi(v3), xu.y, s3);
          s4 = fmaf(bflo(v4), xu.x, s4); s4 = fmaf(bfhi(v4), xu.y, s4);
        }
        s1 = wsum(s1); s2 = wsum(s2); s3 = wsum(s3); s4 = wsum(s4);
        if (lane == 0) {
          ghs_s[sr] = s1 + bSH[q]; ghg_s[sr] = s2 + bGH[q];
          sxu[sr] = s3 + bSI[q];   gxu[sr] = s4 + bGI[q];
        }
      }
    }
    if (t > 0 && wave < 3) {
      const float2* br = (const float2*)(g_buf + (size_t)(t - 1) * E2_);
      float s = 0.f;
#pragma unroll
      for (int pp = 0; pp < 12; ++pp) {
        int j = lane + 64 * pp;
        float2 x = br[j];
        s = fmaf(wKV[2 * pp], x.x, s);
        s = fmaf(wKV[2 * pp + 1], x.y, s);
      }
      s = wsum(s);
      if (lane == 0) V_lds[t - 1][wave] = s + (wave == 0 ? vb0 : (wave == 1 ? vb1 : vb2));
    }
    gbar(++bt);

    // ---------- P1: max-subtracted softmax + att (3 dims per block) ----------
    if (t == 0) {
      if (tid < 3) { float v = a.att0[h0 + tid]; att_s[tid] = v; g_att[h0 + tid] = v; }
    } else {
      float sc = (tid <= t) ? g_scores[tid] : -3.0e38f;
      float m = wmax(sc);
      if (lane == 0) pmax[wave] = m;
      __syncthreads();
      float mall = fmaxf(fmaxf(pmax[0], pmax[1]), fmaxf(pmax[2], pmax[3]));
      float e = 0.f, n0 = 0.f, n1 = 0.f, n2 = 0.f;
      if (tid <= t) {
        e = expf(sc - mall);
        if (tid < t) { n0 = e * V_lds[tid][0]; n1 = e * V_lds[tid][1]; n2 = e * V_lds[tid][2]; }
        else         { n0 = e * vb0; n1 = e * vb1; n2 = e * vb2; }
      }
      e = wsum(e); n0 = wsum(n0); n1 = wsum(n1); n2 = wsum(n2);
      if (lane == 0) { pnum[wave][0] = e; pnum[wave][1] = n0; pnum[wave][2] = n1; pnum[wave][3] = n2; }
      __syncthreads();
      if (tid < 3) {
        float den = pnum[0][0] + pnum[1][0] + pnum[2][0] + pnum[3][0];
        float nn = pnum[0][tid + 1] + pnum[1][tid + 1] + pnum[2][tid + 1] + pnum[3][tid + 1];
        float v = nn / den;
        att_s[tid] = v; g_att[h0 + tid] = v;
      }
    }
    gbar(++bt);

    // ---------- P2: speaker GRU ----------
#pragma unroll
    for (int q = 0; q < 5; ++q) {
      int sr = wave + 4 * q;
      if (sr < 18) {
        const float2* xv = (const float2*)g_att;
        float s = 0.f;
#pragma unroll
        for (int pp = 0; pp < 6; ++pp) {
          int j = lane + 64 * pp;
          u32 v = wSA[q][pp];
          float2 x = xv[j];
          s = fmaf(bflo(v), x.x, s); s = fmaf(bfhi(v), x.y, s);
        }
        s = wsum(s);
        if (lane == 0) gxs[sr] = s;
      }
    }
    __syncthreads();
    if (tid < 6) {
      int dir = tid / 3, d = tid - dir * 3, h = h0 + d;
      float xr = gxs[dir * 9 + d]     + sxu[dir * 9 + d];
      float xz = gxs[dir * 9 + 3 + d] + sxu[dir * 9 + 3 + d];
      float xn = gxs[dir * 9 + 6 + d] + sxu[dir * 9 + 6 + d];
      float hr = ghs_s[dir * 9 + d], hz = ghs_s[dir * 9 + 3 + d], hn = ghs_s[dir * 9 + 6 + d];
      float hp = g_hstate[(size_t)(sp * 2 + dir) * E_ + h];
      float r = 1.f / (1.f + expf(-(xr + hr)));
      float z = 1.f / (1.f + expf(-(xz + hz)));
      float n = tanhf(xn + r * hn);
      float hnew = (1.f - z) * n + z * hp;
      g_hstate[(size_t)(sp * 2 + dir) * E_ + h] = hnew;
      float resid = dir ? a.dialogue[(size_t)t * E_ + h] : att_s[d];
      float so = hnew + resid;
      g_so[dir * E_ + h] = so;
      a.out[(size_t)U_ * E2_ + (size_t)t * E2_ + dir * E_ + h] = so;
    }
    gbar(++bt);

    // ---------- P3: global GRU ----------
#pragma unroll
    for (int q = 0; q < 5; ++q) {
      int sr = wave + 4 * q;
      if (sr < 18) {
        const float2* xv = (const float2*)g_so;
        float s = 0.f;
#pragma unroll
        for (int pp = 0; pp < 12; ++pp) {
          int j = lane + 64 * pp;
          u32 v = wGSO[q][pp];
          float2 x = xv[j];
          s = fmaf(bflo(v), x.x, s); s = fmaf(bfhi(v), x.y, s);
        }
        s = wsum(s);
        if (lane == 0) gxs[sr] = s;
      }
    }
    __syncthreads();
    if (tid < 6) {
      int dir = tid / 3, d = tid - dir * 3, h = h0 + d;
      float xr = gxs[dir * 9 + d]     + gxu[dir * 9 + d];
      float xz = gxs[dir * 9 + 3 + d] + gxu[dir * 9 + 3 + d];
      float xn = gxs[dir * 9 + 6 + d] + gxu[dir * 9 + 6 + d];
      float hr = ghg_s[dir * 9 + d], hz = ghg_s[dir * 9 + 3 + d], hn = ghg_s[dir * 9 + 6 + d];
      float hp = g_gh[dir * E_ + h];
      float r = 1.f / (1.f + expf(-(xr + hr)));
      float z = 1.f / (1.f + expf(-(xz + hz)));
      float n = tanhf(xn + r * hn);
      float hnew = (1.f - z) * n + z * hp;
      g_gh[dir * E_ + h] = hnew;
      g_buf[(size_t)t * E2_ + dir * E_ + h] = hnew;
      a.out[(size_t)t * E2_ + dir * E_ + h] = hnew;
    }
    gbar(++bt);
  }
}

// ---------------- host ----------------
extern "C" void kernel_launch(void* const* d_in, const int* in_sizes, int n_in,
                              void* d_out, int out_size, void* d_ws, size_t ws_size,
                              hipStream_t stream)
{
  (void)in_sizes; (void)n_in; (void)out_size; (void)d_ws; (void)ws_size;
  const float* dialogue = (const float*)d_in[0];
  const int* speakers = (const int*)d_in[1];
  const float* Wq = (const float*)d_in[2];
  const float* bq = (const float*)d_in[3];
  const float* Wk = (const float*)d_in[4];
  const float* bk = (const float*)d_in[5];
  const float* Wv = (const float*)d_in[6];
  const float* bv = (const float*)d_in[7];
  const float* sWih_f = (const float*)d_in[8];
  const float* sWhh_f = (const float*)d_in[9];
  const float* sbih_f = (const float*)d_in[10];
  const float* sbhh_f = (const float*)d_in[11];
  const float* sWih_b = (const float*)d_in[12];
  const float* sWhh_b = (const float*)d_in[13];
  const float* sbih_b = (const float*)d_in[14];
  const float* sbhh_b = (const float*)d_in[15];
  const float* gWih_f = (const float*)d_in[16];
  const float* gWhh_f = (const float*)d_in[17];
  const float* gbih_f = (const float*)d_in[18];
  const float* gbhh_f = (const float*)d_in[19];
  const float* gWih_b = (const float*)d_in[20];
  const float* gWhh_b = (const float*)d_in[21];
  const float* gbih_b = (const float*)d_in[22];
  const float* gbhh_b = (const float*)d_in[23];
  const float* h0_global = (const float*)d_in[24];
  const float* h0_speaker = (const float*)d_in[25];
  const float* att0 = (const float*)d_in[26];

  init_kernel<<<dim3(76), dim3(256), 0, stream>>>(h0_global, h0_speaker, bk, Wv, bv);

  // g_Q = D @ Wq + bq
  gemm32<0, 0, 0, 0><<<dim3(12, 4), dim3(256), 0, stream>>>(
      dialogue, 768, Wq, 768, bq, 1.f, 768, 256, 768, 768);
  // g_WQg = g_Q @ Wk^T / norm
  gemm32<1, 1, 1, 0><<<dim3(24, 4), dim3(256), 0, stream>>>(
      nullptr, 768, Wk, 768, nullptr, 1.f / NORM_, 1536, 256, 1536, 768);
  // g_WKVT[e][k] = (Wk @ Wv)[k][e]
  gemm32<0, 0, 2, 1><<<dim3(12, 24), dim3(256), 0, stream>>>(
      Wk, 768, Wv, 768, nullptr, 1.f, 1536, 1536, 768, 768);

  SeqArgs args;
  args.dialogue = dialogue;
  args.sWih_f = sWih_f; args.sWih_b = sWih_b; args.sWhh_f = sWhh_f; args.sWhh_b = sWhh_b;
  args.sbih_f = sbih_f; args.sbih_b = sbih_b; args.sbhh_f = sbhh_f; args.sbhh_b = sbhh_b;
  args.gWih_f = gWih_f; args.gWih_b = gWih_b; args.gWhh_f = gWhh_f; args.gWhh_b = gWhh_b;
  args.gbih_f = gbih_f; args.gbih_b = gbih_b; args.gbhh_f = gbhh_f; args.gbhh_b = gbhh_b;
  args.att0 = att0; args.speakers = speakers;
  args.out = (float*)d_out;

  seq_kernel<<<dim3(256), dim3(256), 0, stream>>>(args);
}

// Round 9
// 14514.355 us; speedup vs baseline: 1.7927x; 1.0915x over previous
//
#include <hip/hip_runtime.h>
#include <hip/hip_bf16.h>

#define E_ 768
#define E2_ 1536
#define E3_ 2304
#define U_ 256
#define NORM_ 27.712812921102035f

typedef unsigned int u32;
typedef unsigned long long u64;

// ---------------- static device workspace (~8.3 MB) ----------------
__device__ __align__(16) float g_Q[U_ * E_];       // D @ Wq + bq
__device__ __align__(16) float g_WQg[U_ * E2_];    // (Wk @ q_t)/norm, row t
__device__ __align__(16) float g_WKVT[E_ * E2_];   // (Wk@Wv)^T : [e][k]
__device__ __align__(16) float g_buf[U_ * E2_];    // attention memory
__device__ __align__(16) float g_vb[E_];           // bk@Wv + bv
__device__ __align__(16) float g_scores[U_];
__device__ __align__(16) float g_att[E_];
__device__ __align__(16) float g_so[E2_];
__device__ __align__(16) float g_gh[E2_];
__device__ __align__(16) float g_hstate[8 * E2_];
// hierarchical barrier state: 16 arrival counters on separate 128B lines + epoch
__device__ __align__(128) int g_cnt[16 * 32];
__device__ __align__(128) int g_epoch;

__device__ __forceinline__ float bflo(u32 v){ return __uint_as_float(v << 16); }
__device__ __forceinline__ float bfhi(u32 v){ return __uint_as_float(v & 0xffff0000u); }

// pack two fp32 into one u32 holding two bf16 (RNE)
__device__ __forceinline__ u32 packbf(float lo, float hi){
  u32 a = __float_as_uint(lo), b = __float_as_uint(hi);
  a = (a + 0x7FFFu + ((a >> 16) & 1u)) >> 16;
  b = (b + 0x7FFFu + ((b >> 16) & 1u)) & 0xFFFF0000u;
  return (a & 0xFFFFu) | b;
}

__device__ __forceinline__ float wsum(float v){
#pragma unroll
  for (int o = 32; o > 0; o >>= 1) v += __shfl_xor(v, o, 64);
  return v;
}
__device__ __forceinline__ float wmax(float v){
#pragma unroll
  for (int o = 32; o > 0; o >>= 1) v = fmaxf(v, __shfl_xor(v, o, 64));
  return v;
}

// ---------------- init: barrier words, hstate/gh (blocks 0..63), vb (64..75) ----------------
__global__ __launch_bounds__(256) void init_kernel(const float* h0g, const float* h0s,
                                                   const float* bk, const float* Wv,
                                                   const float* bv)
{
  __shared__ float acc4[4][64];
  int tid = threadIdx.x;
  if (blockIdx.x < 64) {
    int i = blockIdx.x * 256 + tid;
    int n = 64 * 256;
    if (i < 16 * 32) g_cnt[i] = 0;
    if (i == 0) g_epoch = 0;
    for (int j = i; j < 8 * E2_; j += n) g_hstate[j] = h0s[j % E2_];
    for (int j = i; j < E2_; j += n) g_gh[j] = h0g[j];
  } else {
    int b = blockIdx.x - 64;          // 0..11
    int o = b * 64 + (tid & 63);
    int w = tid >> 6;
    float s = 0.f;
    for (int i2 = w * 192; i2 < w * 192 + 192; ++i2)
      s = fmaf(bk[i2], Wv[(size_t)i2 * E_ + o], s);
    acc4[w][tid & 63] = s;
    __syncthreads();
    if (w == 0)
      g_vb[o] = acc4[0][tid & 63] + acc4[1][tid & 63] + acc4[2][tid & 63] + acc4[3][tid & 63] + bv[o];
  }
}

// ---------------- fp32 tiled GEMM: C = scale*(A@B) + bias ----------------
template<int ASRC, int BNK, int DST, int TC>
__global__ __launch_bounds__(256) void gemm32(const float* __restrict__ Aext, int lda,
                                              const float* __restrict__ B, int ldb,
                                              const float* __restrict__ bias, float scale,
                                              int ldc, int M, int N, int K)
{
  const float* A = (ASRC == 1) ? g_Q : Aext;
  float* C = (DST == 0) ? g_Q : (DST == 1) ? g_WQg : g_WKVT;
  __shared__ float As[64][17];
  __shared__ float Bs[16][65];
  int tid = threadIdx.x;
  int tx = tid & 15, ty = tid >> 4;
  int m0 = blockIdx.y * 64, n0 = blockIdx.x * 64;
  float acc[4][4] = {{0.f}};
  for (int k0 = 0; k0 < K; k0 += 16) {
#pragma unroll
    for (int i = 0; i < 4; ++i) {
      int li = tid + 256 * i;
      int m = li >> 4, kk = li & 15;
      As[m][kk] = A[(size_t)(m0 + m) * lda + k0 + kk];
    }
#pragma unroll
    for (int i = 0; i < 4; ++i) {
      int li = tid + 256 * i;
      if (BNK) {
        int n = li >> 4, kk = li & 15;
        Bs[kk][n] = B[(size_t)(n0 + n) * ldb + k0 + kk];
      } else {
        int kk = li >> 6, n = li & 63;
        Bs[kk][n] = B[(size_t)(k0 + kk) * ldb + n0 + n];
      }
    }
    __syncthreads();
#pragma unroll
    for (int kk = 0; kk < 16; ++kk) {
      float av[4], bv4[4];
#pragma unroll
      for (int i = 0; i < 4; ++i) av[i] = As[ty * 4 + i][kk];
#pragma unroll
      for (int j = 0; j < 4; ++j) bv4[j] = Bs[kk][tx * 4 + j];
#pragma unroll
      for (int i = 0; i < 4; ++i)
#pragma unroll
        for (int j = 0; j < 4; ++j) acc[i][j] = fmaf(av[i], bv4[j], acc[i][j]);
    }
    __syncthreads();
  }
#pragma unroll
  for (int i = 0; i < 4; ++i)
#pragma unroll
    for (int j = 0; j < 4; ++j) {
      int m = m0 + ty * 4 + i, n = n0 + tx * 4 + j;
      float c = acc[i][j] * scale;
      if (bias) c += bias[n];
      if (TC) C[(size_t)n * ldc + m] = c;
      else    C[(size_t)m * ldc + n] = c;
    }
}

// ---------------- persistent sequential kernel ----------------
struct SeqArgs {
  const float *dialogue, *sWih_f, *sWih_b, *sWhh_f, *sWhh_b,
      *sbih_f, *sbih_b, *sbhh_f, *sbhh_b,
      *gWih_f, *gWih_b, *gWhh_f, *gWhh_b, *gbih_f, *gbih_b, *gbhh_f, *gbhh_b,
      *att0;
  const int* speakers;
  float* out;   // fp32: [U*2E buf][U*2E so]
};

// Hierarchical barrier: 16 padded arrival counters (blockIdx&15) -> parallel
// RMW streams; root (block 0) polls the 16 counters and publishes the epoch;
// other leaders poll the epoch with s_sleep backoff. Fences give agent-scope
// release/acquire around the whole exchange.
__device__ __forceinline__ void gbar(int target)
{
  __syncthreads();
  if (threadIdx.x == 0) {
    __builtin_amdgcn_fence(__ATOMIC_RELEASE, "agent");
    __hip_atomic_fetch_add(&g_cnt[(blockIdx.x & 15) * 32], 1,
                           __ATOMIC_RELAXED, __HIP_MEMORY_SCOPE_AGENT);
    if (blockIdx.x == 0) {
      int need = 256 * target;
      for (;;) {
        int sum = 0;
#pragma unroll
        for (int i = 0; i < 16; ++i)
          sum += __hip_atomic_load(&g_cnt[i * 32], __ATOMIC_RELAXED, __HIP_MEMORY_SCOPE_AGENT);
        if (sum >= need) break;
      }
      __builtin_amdgcn_fence(__ATOMIC_ACQUIRE, "agent");
      __builtin_amdgcn_fence(__ATOMIC_RELEASE, "agent");
      __hip_atomic_store(&g_epoch, target, __ATOMIC_RELAXED, __HIP_MEMORY_SCOPE_AGENT);
    } else {
      while (__hip_atomic_load(&g_epoch, __ATOMIC_RELAXED, __HIP_MEMORY_SCOPE_AGENT) < target)
        __builtin_amdgcn_s_sleep(2);
    }
    __builtin_amdgcn_fence(__ATOMIC_ACQUIRE, "agent");
  }
  __syncthreads();
}

__global__ __launch_bounds__(256, 1) void seq_kernel(SeqArgs a)
{
  const int tid = threadIdx.x, wg = blockIdx.x;
  const int wave = tid >> 6, lane = tid & 63;
  const int h0 = wg * 3;

  __shared__ float ghs_s[18], ghg_s[18], sxu[18], gxu[18], gxs[18];
  __shared__ float red4[4], att_s[3], pnum[4][4], pmax[4];
  __shared__ float V_lds[U_][3];

  // ---- per-block weight slices: fp32 -> packed bf16 registers ----
  u32 wSA[5][6], wSU[5][6], wSHH[5][6], wGHH[5][6], wGSO[5][12], wGU[5][6];
  float bSH[5], bGH[5], bSI[5], bGI[5];
#pragma unroll
  for (int q = 0; q < 5; ++q) {
    int sr = wave + 4 * q;
    if (sr < 18) {
      int dir = sr / 9, lr = sr - dir * 9, g = lr / 3, d = lr - g * 3;
      int gr = g * E_ + h0 + d;
      const float* pa  = (dir ? a.sWih_b : a.sWih_f) + (size_t)gr * E2_;
      const float* ph  = (dir ? a.sWhh_b : a.sWhh_f) + (size_t)gr * E_;
      const float* pgs = (dir ? a.gWih_b : a.gWih_f) + (size_t)gr * E3_;
      const float* pgh = (dir ? a.gWhh_b : a.gWhh_f) + (size_t)gr * E_;
#pragma unroll
      for (int pp = 0; pp < 6; ++pp) {
        int j2 = 2 * (lane + 64 * pp);
        wSA[q][pp]  = packbf(pa[j2], pa[j2 + 1]);
        wSU[q][pp]  = packbf(pa[768 + j2], pa[768 + j2 + 1]);
        wSHH[q][pp] = packbf(ph[j2], ph[j2 + 1]);
        wGHH[q][pp] = packbf(pgh[j2], pgh[j2 + 1]);
        wGU[q][pp]  = packbf(pgs[1536 + j2], pgs[1536 + j2 + 1]);
      }
#pragma unroll
      for (int pp = 0; pp < 12; ++pp) {
        int j2 = 2 * (lane + 64 * pp);
        wGSO[q][pp] = packbf(pgs[j2], pgs[j2 + 1]);
      }
      bSH[q] = (dir ? a.sbhh_b : a.sbhh_f)[gr];
      bSI[q] = (dir ? a.sbih_b : a.sbih_f)[gr];
      bGH[q] = (dir ? a.gbhh_b : a.gbhh_f)[gr];
      bGI[q] = (dir ? a.gbih_b : a.gbih_f)[gr];
    }
  }
  // ---- wKV: 3 columns of Wk@Wv for this block (fp32) ----
  float wKV[24];
  if (wave < 3) {
    const float* kv = g_WKVT + (size_t)(h0 + wave) * E2_;
#pragma unroll
    for (int pp = 0; pp < 12; ++pp) {
      int j2 = 2 * (lane + 64 * pp);
      wKV[2 * pp] = kv[j2]; wKV[2 * pp + 1] = kv[j2 + 1];
    }
  }
  const float vb0 = g_vb[h0], vb1 = g_vb[h0 + 1], vb2 = g_vb[h0 + 2];

  int bt = 0;
  for (int t = 0; t < U_; ++t) {
    const int sp = a.speakers[t] & 7;
    const float2* uv = (const float2*)(a.dialogue + (size_t)t * E_);   // 384 float2

    // ---------- P0: scores, recurrent-h + u-part matvecs, V[t-1] slice ----------
    if (wg < t) {
      const float2* br = (const float2*)(g_buf + (size_t)wg * E2_);
      const float2* wq = (const float2*)(g_WQg + (size_t)t * E2_);
      float s = 0.f;
#pragma unroll
      for (int pp = 0; pp < 3; ++pp) {
        int j = tid + 256 * pp;
        float2 x = br[j];
        float2 w = wq[j];
        s = fmaf(x.x, w.x, s);
        s = fmaf(x.y, w.y, s);
      }
      s = wsum(s);
      if (lane == 0) red4[wave] = s;
      __syncthreads();
      if (tid == 0) g_scores[wg] = red4[0] + red4[1] + red4[2] + red4[3];
    } else if (wg == t) {
      if (tid == 0) g_scores[wg] = 0.f;  // buf row t zero; const shift dropped (softmax-inv)
    }
#pragma unroll
    for (int q = 0; q < 5; ++q) {
      int sr = wave + 4 * q;
      if (sr < 18) {
        int dir = sr / 9;
        const float2* hv = (const float2*)(g_hstate + (size_t)(sp * 2 + dir) * E_);
        const float2* gv = (const float2*)(g_gh + (size_t)dir * E_);
        float s1 = 0.f, s2 = 0.f, s3 = 0.f, s4 = 0.f;
#pragma unroll
        for (int pp = 0; pp < 6; ++pp) {
          int j = lane + 64 * pp;
          u32 v1 = wSHH[q][pp], v2 = wGHH[q][pp], v3 = wSU[q][pp], v4 = wGU[q][pp];
          float2 xh = hv[j];
          float2 xg = gv[j];
          float2 xu = uv[j];
          s1 = fmaf(bflo(v1), xh.x, s1); s1 = fmaf(bfhi(v1), xh.y, s1);
          s2 = fmaf(bflo(v2), xg.x, s2); s2 = fmaf(bfhi(v2), xg.y, s2);
          s3 = fmaf(bflo(v3), xu.x, s3); s3 = fmaf(bfhi(v3), xu.y, s3);
          s4 = fmaf(bflo(v4), xu.x, s4); s4 = fmaf(bfhi(v4), xu.y, s4);
        }
        s1 = wsum(s1); s2 = wsum(s2); s3 = wsum(s3); s4 = wsum(s4);
        if (lane == 0) {
          ghs_s[sr] = s1 + bSH[q]; ghg_s[sr] = s2 + bGH[q];
          sxu[sr] = s3 + bSI[q];   gxu[sr] = s4 + bGI[q];
        }
      }
    }
    if (t > 0 && wave < 3) {
      const float2* br = (const float2*)(g_buf + (size_t)(t - 1) * E2_);
      float s = 0.f;
#pragma unroll
      for (int pp = 0; pp < 12; ++pp) {
        int j = lane + 64 * pp;
        float2 x = br[j];
        s = fmaf(wKV[2 * pp], x.x, s);
        s = fmaf(wKV[2 * pp + 1], x.y, s);
      }
      s = wsum(s);
      if (lane == 0) V_lds[t - 1][wave] = s + (wave == 0 ? vb0 : (wave == 1 ? vb1 : vb2));
    }
    gbar(++bt);

    // ---------- P1: max-subtracted softmax + att (3 dims per block) ----------
    if (t == 0) {
      if (tid < 3) { float v = a.att0[h0 + tid]; att_s[tid] = v; g_att[h0 + tid] = v; }
    } else {
      float sc = (tid <= t) ? g_scores[tid] : -3.0e38f;
      float m = wmax(sc);
      if (lane == 0) pmax[wave] = m;
      __syncthreads();
      float mall = fmaxf(fmaxf(pmax[0], pmax[1]), fmaxf(pmax[2], pmax[3]));
      float e = 0.f, n0 = 0.f, n1 = 0.f, n2 = 0.f;
      if (tid <= t) {
        e = expf(sc - mall);
        if (tid < t) { n0 = e * V_lds[tid][0]; n1 = e * V_lds[tid][1]; n2 = e * V_lds[tid][2]; }
        else         { n0 = e * vb0; n1 = e * vb1; n2 = e * vb2; }
      }
      e = wsum(e); n0 = wsum(n0); n1 = wsum(n1); n2 = wsum(n2);
      if (lane == 0) { pnum[wave][0] = e; pnum[wave][1] = n0; pnum[wave][2] = n1; pnum[wave][3] = n2; }
      __syncthreads();
      if (tid < 3) {
        float den = pnum[0][0] + pnum[1][0] + pnum[2][0] + pnum[3][0];
        float nn = pnum[0][tid + 1] + pnum[1][tid + 1] + pnum[2][tid + 1] + pnum[3][tid + 1];
        float v = nn / den;
        att_s[tid] = v; g_att[h0 + tid] = v;
      }
    }
    gbar(++bt);

    // ---------- P2: speaker GRU ----------
#pragma unroll
    for (int q = 0; q < 5; ++q) {
      int sr = wave + 4 * q;
      if (sr < 18) {
        const float2* xv = (const float2*)g_att;
        float s = 0.f;
#pragma unroll
        for (int pp = 0; pp < 6; ++pp) {
          int j = lane + 64 * pp;
          u32 v = wSA[q][pp];
          float2 x = xv[j];
          s = fmaf(bflo(v), x.x, s); s = fmaf(bfhi(v), x.y, s);
        }
        s = wsum(s);
        if (lane == 0) gxs[sr] = s;
      }
    }
    __syncthreads();
    if (tid < 6) {
      int dir = tid / 3, d = tid - dir * 3, h = h0 + d;
      float xr = gxs[dir * 9 + d]     + sxu[dir * 9 + d];
      float xz = gxs[dir * 9 + 3 + d] + sxu[dir * 9 + 3 + d];
      float xn = gxs[dir * 9 + 6 + d] + sxu[dir * 9 + 6 + d];
      float hr = ghs_s[dir * 9 + d], hz = ghs_s[dir * 9 + 3 + d], hn = ghs_s[dir * 9 + 6 + d];
      float hp = g_hstate[(size_t)(sp * 2 + dir) * E_ + h];
      float r = 1.f / (1.f + expf(-(xr + hr)));
      float z = 1.f / (1.f + expf(-(xz + hz)));
      float n = tanhf(xn + r * hn);
      float hnew = (1.f - z) * n + z * hp;
      g_hstate[(size_t)(sp * 2 + dir) * E_ + h] = hnew;
      float resid = dir ? a.dialogue[(size_t)t * E_ + h] : att_s[d];
      float so = hnew + resid;
      g_so[dir * E_ + h] = so;
      a.out[(size_t)U_ * E2_ + (size_t)t * E2_ + dir * E_ + h] = so;
    }
    gbar(++bt);

    // ---------- P3: global GRU ----------
#pragma unroll
    for (int q = 0; q < 5; ++q) {
      int sr = wave + 4 * q;
      if (sr < 18) {
        const float2* xv = (const float2*)g_so;
        float s = 0.f;
#pragma unroll
        for (int pp = 0; pp < 12; ++pp) {
          int j = lane + 64 * pp;
          u32 v = wGSO[q][pp];
          float2 x = xv[j];
          s = fmaf(bflo(v), x.x, s); s = fmaf(bfhi(v), x.y, s);
        }
        s = wsum(s);
        if (lane == 0) gxs[sr] = s;
      }
    }
    __syncthreads();
    if (tid < 6) {
      int dir = tid / 3, d = tid - dir * 3, h = h0 + d;
      float xr = gxs[dir * 9 + d]     + gxu[dir * 9 + d];
      float xz = gxs[dir * 9 + 3 + d] + gxu[dir * 9 + 3 + d];
      float xn = gxs[dir * 9 + 6 + d] + gxu[dir * 9 + 6 + d];
      float hr = ghg_s[dir * 9 + d], hz = ghg_s[dir * 9 + 3 + d], hn = ghg_s[dir * 9 + 6 + d];
      float hp = g_gh[dir * E_ + h];
      float r = 1.f / (1.f + expf(-(xr + hr)));
      float z = 1.f / (1.f + expf(-(xz + hz)));
      float n = tanhf(xn + r * hn);
      float hnew = (1.f - z) * n + z * hp;
      g_gh[dir * E_ + h] = hnew;
      g_buf[(size_t)t * E2_ + dir * E_ + h] = hnew;
      a.out[(size_t)t * E2_ + dir * E_ + h] = hnew;
    }
    gbar(++bt);
  }
}

// ---------------- host ----------------
extern "C" void kernel_launch(void* const* d_in, const int* in_sizes, int n_in,
                              void* d_out, int out_size, void* d_ws, size_t ws_size,
                              hipStream_t stream)
{
  (void)in_sizes; (void)n_in; (void)out_size; (void)d_ws; (void)ws_size;
  const float* dialogue = (const float*)d_in[0];
  const int* speakers = (const int*)d_in[1];
  const float* Wq = (const float*)d_in[2];
  const float* bq = (const float*)d_in[3];
  const float* Wk = (const float*)d_in[4];
  const float* bk = (const float*)d_in[5];
  const float* Wv = (const float*)d_in[6];
  const float* bv = (const float*)d_in[7];
  const float* sWih_f = (const float*)d_in[8];
  const float* sWhh_f = (const float*)d_in[9];
  const float* sbih_f = (const float*)d_in[10];
  const float* sbhh_f = (const float*)d_in[11];
  const float* sWih_b = (const float*)d_in[12];
  const float* sWhh_b = (const float*)d_in[13];
  const float* sbih_b = (const float*)d_in[14];
  const float* sbhh_b = (const float*)d_in[15];
  const float* gWih_f = (const float*)d_in[16];
  const float* gWhh_f = (const float*)d_in[17];
  const float* gbih_f = (const float*)d_in[18];
  const float* gbhh_f = (const float*)d_in[19];
  const float* gWih_b = (const float*)d_in[20];
  const float* gWhh_b = (const float*)d_in[21];
  const float* gbih_b = (const float*)d_in[22];
  const float* gbhh_b = (const float*)d_in[23];
  const float* h0_global = (const float*)d_in[24];
  const float* h0_speaker = (const float*)d_in[25];
  const float* att0 = (const float*)d_in[26];

  init_kernel<<<dim3(76), dim3(256), 0, stream>>>(h0_global, h0_speaker, bk, Wv, bv);

  // g_Q = D @ Wq + bq
  gemm32<0, 0, 0, 0><<<dim3(12, 4), dim3(256), 0, stream>>>(
      dialogue, 768, Wq, 768, bq, 1.f, 768, 256, 768, 768);
  // g_WQg = g_Q @ Wk^T / norm
  gemm32<1, 1, 1, 0><<<dim3(24, 4), dim3(256), 0, stream>>>(
      nullptr, 768, Wk, 768, nullptr, 1.f / NORM_, 1536, 256, 1536, 768);
  // g_WKVT[e][k] = (Wk @ Wv)[k][e]
  gemm32<0, 0, 2, 1><<<dim3(12, 24), dim3(256), 0, stream>>>(
      Wk, 768, Wv, 768, nullptr, 1.f, 1536, 1536, 768, 768);

  SeqArgs args;
  args.dialogue = dialogue;
  args.sWih_f = sWih_f; args.sWih_b = sWih_b; args.sWhh_f = sWhh_f; args.sWhh_b = sWhh_b;
  args.sbih_f = sbih_f; args.sbih_b = sbih_b; args.sbhh_f = sbhh_f; args.sbhh_b = sbhh_b;
  args.gWih_f = gWih_f; args.gWih_b = gWih_b; args.gWhh_f = gWhh_f; args.gWhh_b = gWhh_b;
  args.gbih_f = gbih_f; args.gbih_b = gbih_b; args.gbhh_f = gbhh_f; args.gbhh_b = gbhh_b;
  args.att0 = att0; args.speakers = speakers;
  args.out = (float*)d_out;

  seq_kernel<<<dim3(256), dim3(256), 0, stream>>>(args);
}